// Round 11
// baseline (208.607 us; speedup 1.0000x reference)
//
#include <hip/hip_runtime.h>
#include <hip/hip_bf16.h>

#define BF16 __hip_bfloat16

typedef __attribute__((ext_vector_type(8))) short bf16x8;
typedef __attribute__((ext_vector_type(4))) float f32x4;
typedef __attribute__((ext_vector_type(4))) unsigned short ushort4v;
typedef __attribute__((ext_vector_type(4))) float float4v;

#define LOG2E 1.44269504089f

__device__ __forceinline__ unsigned short f2bf(float f) {
  BF16 h = __float2bfloat16(f);
  union { BF16 h; unsigned short u; } cv;
  cv.h = h;
  return cv.u;
}

// Direct global->LDS async copy, 16B per lane. LDS dest is wave-uniform base
// + lane*16 (HW rule); swizzling is done on the GLOBAL source address.
__device__ __forceinline__ void gload_lds16(const BF16* g, BF16* s) {
  __builtin_amdgcn_global_load_lds(
      (const __attribute__((address_space(1))) void*)g,
      (__attribute__((address_space(3))) void*)s, 16, 0, 0);
}

// ---------------------------------------------------------------------------
// Kernel 1: fused GroupNorm stats (+per-channel affine precompute) and
// weight fp32->bf16 casts.
// ---------------------------------------------------------------------------
__global__ __launch_bounds__(256) void stats_cast_kernel(const float* __restrict__ x,
                                                         const float* __restrict__ gw,
                                                         const float* __restrict__ gb,
                                                         const float* __restrict__ qw,
                                                         const float* __restrict__ pw,
                                                         float2* __restrict__ stats,
                                                         BF16* __restrict__ wq,
                                                         BF16* __restrict__ wp) {
  const int L = blockIdx.x;
  if (L < 256) {
    const int bb = L & 7, g = L >> 3;   // batch = XCD
    const float* xg = x + (size_t)(bb * 512 + g * 16) * 1024;
    float s = 0.f, ss = 0.f;
    const float4v* x4 = (const float4v*)xg;
    for (int i = threadIdx.x; i < 4096; i += 256) {
      float4v v = x4[i];
      s  += v[0] + v[1] + v[2] + v[3];
      ss += v[0] * v[0] + v[1] * v[1] + v[2] * v[2] + v[3] * v[3];
    }
    for (int off = 32; off > 0; off >>= 1) {
      s  += __shfl_down(s, off, 64);
      ss += __shfl_down(ss, off, 64);
    }
    __shared__ float sred[8];
    const int wv = threadIdx.x >> 6;
    if ((threadIdx.x & 63) == 0) { sred[wv] = s; sred[4 + wv] = ss; }
    __syncthreads();
    const float S  = sred[0] + sred[1] + sred[2] + sred[3];
    const float SS = sred[4] + sred[5] + sred[6] + sred[7];
    const float mean = S * (1.f / 16384.f);
    const float var  = SS * (1.f / 16384.f) - mean * mean;
    const float rstd = rsqrtf(var + 1e-5f);
    if (threadIdx.x < 16) {
      const int c = g * 16 + threadIdx.x;
      const float aw = gw[c] * rstd;
      float2 st; st.x = aw; st.y = gb[c] - mean * aw;
      stats[bb * 512 + c] = st;
    }
  } else {
    const int i4 = (L - 256) * 256 + threadIdx.x;  // float4 index
    if (i4 < 196608) {            // qkv_w: 1536*512/4
      float4v v = ((const float4v*)qw)[i4];
      ushort4v pk;
      #pragma unroll
      for (int r = 0; r < 4; ++r) pk[r] = f2bf(v[r]);
      *(ushort4v*)&wq[i4 * 4] = pk;
    } else {                      // proj_w: 512*512/4
      const int j = i4 - 196608;
      float4v v = ((const float4v*)pw)[j];
      ushort4v pk;
      #pragma unroll
      for (int r = 0; r < 4; ++r) pk[r] = f2bf(v[r]);
      *(ushort4v*)&wp[j * 4] = pk;
    }
  }
}

// ---------------------------------------------------------------------------
// Kernel 2: GroupNorm apply + transpose -> h_t[b][n][c] bf16, coalesced.
// ---------------------------------------------------------------------------
__global__ __launch_bounds__(256) void gn_apply_kernel(const float* __restrict__ x,
                                                       const float2* __restrict__ stats,
                                                       BF16* __restrict__ h_t) {
  const int L = blockIdx.x;           // 0..255
  const int b = L & 7, pxt = L >> 3;  // batch = XCD; 32 px per tile
  const int t = threadIdx.x;
  __shared__ __align__(16) BF16 Lt[128 * 8 * 4];  // 128 ch x 32 px, 8B granules

  for (int ct = 0; ct < 4; ++ct) {    // 128-channel tiles
    if (ct) __syncthreads();
    #pragma unroll
    for (int k = 0; k < 4; ++k) {
      const int i = k * 256 + t;
      const int ch_l = i >> 3, f4l = i & 7;
      const int cg = ct * 128 + ch_l;
      const float2 st = stats[b * 512 + cg];
      const float4v v =
          ((const float4v*)x)[((size_t)(b * 512 + cg)) * 256 + pxt * 8 + f4l];
      ushort4v pk;
      #pragma unroll
      for (int r = 0; r < 4; ++r) pk[r] = f2bf(v[r] * st.x + st.y);
      const int s = f4l ^ (ch_l & 7) ^ ((ch_l >> 3) & 7);
      *(ushort4v*)&Lt[(ch_l * 8 + s) * 4] = pk;
    }
    __syncthreads();
    #pragma unroll
    for (int rr = 0; rr < 2; ++rr) {
      const int px_l = (rr * 256 + t) >> 4;   // 0..31
      const int c16 = t & 15;
      union { unsigned short u[8]; bf16x8 v8; } o;
      #pragma unroll
      for (int cc = 0; cc < 8; ++cc) {
        const int ch = c16 * 8 + cc;
        const int s = (px_l >> 2) ^ (ch & 7) ^ ((ch >> 3) & 7);
        o.u[cc] = *(const unsigned short*)&Lt[(ch * 8 + s) * 4 + (px_l & 3)];
      }
      *(bf16x8*)&h_t[((size_t)(b * 1024 + pxt * 32 + px_l)) * 512 + ct * 128 +
                     c16 * 8] = o.v8;
    }
  }
}

// ---------------------------------------------------------------------------
// GEMM core. Tile 128x128, BK=64, 4 waves, bf16 MFMA; global_load_lds staging
// with inverse chunk-XOR on the global source (m173 pattern).
// ---------------------------------------------------------------------------
#define GEMM_CORE(A, B, Al, Bl)                                                \
  const int tid = threadIdx.x, l = tid & 63, wv = tid >> 6;                    \
  const int wm = wv >> 1, wn = wv & 1;                                         \
  const int lc = l & 15, lh = l >> 4;                                          \
  f32x4 acc[4][4] = {};                                                        \
  int srow[4], scg[4];                                                         \
  _Pragma("unroll")                                                            \
  for (int t = 0; t < 4; ++t) {                                                \
    int cidx = t * 256 + wv * 64 + l;                                          \
    srow[t] = cidx >> 3;                                                       \
    scg[t]  = (cidx & 7) ^ (srow[t] & 7);                                      \
  }                                                                            \
  for (int kt = 0; kt < 8; ++kt) {                                             \
    const int k0 = kt * 64;                                                    \
    __syncthreads();                                                           \
    _Pragma("unroll")                                                          \
    for (int t = 0; t < 4; ++t) {                                              \
      gload_lds16(&A[(size_t)srow[t] * 512 + k0 + scg[t] * 8],                 \
                  &Al[(t * 256 + wv * 64) * 8]);                               \
      gload_lds16(&B[(size_t)srow[t] * 512 + k0 + scg[t] * 8],                 \
                  &Bl[(t * 256 + wv * 64) * 8]);                               \
    }                                                                          \
    __syncthreads();                                                           \
    _Pragma("unroll")                                                          \
    for (int ks = 0; ks < 2; ++ks) {                                           \
      bf16x8 af[4], bfr[4];                                                    \
      _Pragma("unroll")                                                        \
      for (int i = 0; i < 4; ++i) {                                            \
        int rA = wm * 64 + i * 16 + lc;                                        \
        int cA = (ks * 4 + lh) ^ (rA & 7);                                     \
        af[i] = *(const bf16x8*)&Al[(rA * 8 + cA) * 8];                        \
        int rB = wn * 64 + i * 16 + lc;                                        \
        int cB = (ks * 4 + lh) ^ (rB & 7);                                     \
        bfr[i] = *(const bf16x8*)&Bl[(rB * 8 + cB) * 8];                       \
      }                                                                        \
      _Pragma("unroll")                                                        \
      for (int i = 0; i < 4; ++i)                                              \
        _Pragma("unroll")                                                      \
        for (int j = 0; j < 4; ++j)                                            \
          acc[i][j] = __builtin_amdgcn_mfma_f32_16x16x32_bf16(af[i], bfr[j],   \
                                                              acc[i][j], 0, 0, 0); \
    }                                                                          \
  }

// QKV GEMM: A = qkv_w bf16 [1536][512]; B = h_t[b] [1024][512].
// Epilogue stages output tile in LDS and writes fully coalesced.
__global__ __launch_bounds__(256) void qkv_gemm_kernel(const BF16* __restrict__ Wq,
                                                       const BF16* __restrict__ Ht,
                                                       const float* __restrict__ bias,
                                                       BF16* __restrict__ q_t,
                                                       BF16* __restrict__ k_t,
                                                       BF16* __restrict__ v_nat) {
  const int L = blockIdx.x;            // 0..767
  const int b = L & 7, w = L >> 3;     // batch = XCD
  const int mt = w % 12, nt = w / 12;
  const int m0 = mt * 128, n0 = nt * 128;
  const BF16* A = Wq + (size_t)m0 * 512;
  const BF16* B = Ht + (size_t)b * 1024 * 512 + (size_t)n0 * 512;
  __shared__ __align__(16) BF16 smem[16384];
  BF16* Al = smem;
  BF16* Bl = smem + 8192;
  GEMM_CORE(A, B, Al, Bl)

  __syncthreads();                     // all frag reads done; reuse smem
  BF16* Et = smem;                     // 16384 BF16 = 32 KiB
  if (mt < 8) {
    const float scale = (mt < 4) ? 0.125f * LOG2E : 1.0f;
    #pragma unroll
    for (int mi = 0; mi < 4; ++mi) {
      const int d0 = mi * 16 + 4 * lh;          // 0..63
      const int o  = m0 + wm * 64 + d0;
      const int g  = d0 >> 3;
      #pragma unroll
      for (int ni = 0; ni < 4; ++ni) {
        const int pixl = wn * 64 + ni * 16 + lc;
        f32x4 a = acc[mi][ni];
        ushort4v pk;
        #pragma unroll
        for (int r = 0; r < 4; ++r) pk[r] = f2bf((a[r] + bias[o + r]) * scale);
        const int s = g ^ (pixl & 7);
        *(ushort4v*)&Et[((wm * 128 + pixl) * 8 + s) * 8 + (d0 & 7)] = pk;
      }
    }
    __syncthreads();
    BF16* dstb = (mt < 4) ? q_t : k_t;
    const int hb0 = (mt & 3) * 2;
    #pragma unroll
    for (int rr = 0; rr < 8; ++rr) {
      const int rowI = rr * 32 + (tid >> 3);    // 0..255
      const int h2 = rowI >> 7, pixl = rowI & 127;
      const int j = tid & 7;
      bf16x8 v = *(const bf16x8*)&Et[(rowI * 8 + (j ^ (pixl & 7))) * 8];
      *(bf16x8*)&dstb[((size_t)(b * 8 + hb0 + h2) * 1024 + n0 + pixl) * 64 +
                      j * 8] = v;
    }
  } else {
    // V: stage [vr_l][pixl] (128x128)
    #pragma unroll
    for (int mi = 0; mi < 4; ++mi) {
      #pragma unroll
      for (int ni = 0; ni < 4; ++ni) {
        const int pixl = wn * 64 + ni * 16 + lc;
        const int gp = pixl >> 3;
        f32x4 a = acc[mi][ni];
        #pragma unroll
        for (int r = 0; r < 4; ++r) {
          const int vr_l = wm * 64 + mi * 16 + 4 * lh + r;
          const int s = gp ^ (vr_l & 15);
          Et[(vr_l * 16 + s) * 8 + (pixl & 7)] =
              __float2bfloat16(a[r] + bias[m0 + vr_l]);
        }
      }
    }
    __syncthreads();
    const int vr0 = m0 - 1024;
    #pragma unroll
    for (int rr = 0; rr < 8; ++rr) {
      const int vr_l = rr * 16 + (tid >> 4);
      const int gp = tid & 15;
      bf16x8 v = *(const bf16x8*)&Et[(vr_l * 16 + (gp ^ (vr_l & 15))) * 8];
      *(bf16x8*)&v_nat[((size_t)(b * 512 + vr0 + vr_l)) * 1024 + n0 + gp * 8] = v;
    }
  }
}

// Proj GEMM + bias + residual. XCD-swizzled: batch == XCD.
__global__ __launch_bounds__(256) void proj_gemm_kernel(const BF16* __restrict__ Wp,
                                                        const BF16* __restrict__ At,
                                                        const float* __restrict__ bias,
                                                        const float* __restrict__ x,
                                                        float* __restrict__ out) {
  const int L = blockIdx.x;            // 0..255
  const int b = L & 7, w = L >> 3;
  const int mt = w & 3, nt = w >> 2;
  const int m0 = mt * 128, n0 = nt * 128;
  const BF16* A = Wp + (size_t)m0 * 512;
  const BF16* B = At + (size_t)b * 1024 * 512 + (size_t)n0 * 512;
  __shared__ __align__(16) BF16 smem[16384];
  BF16* Al = smem;
  BF16* Bl = smem + 8192;
  GEMM_CORE(A, B, Al, Bl)

  const int r0 = lh * 4;
  #pragma unroll
  for (int mi = 0; mi < 4; ++mi) {
    #pragma unroll
    for (int ni = 0; ni < 4; ++ni) {
      const int n = n0 + wn * 64 + ni * 16 + lc;
      f32x4 a = acc[mi][ni];
      #pragma unroll
      for (int r = 0; r < 4; ++r) {
        const int c = m0 + wm * 64 + mi * 16 + r0 + r;
        const size_t idx = ((size_t)(b * 512 + c)) * 1024 + n;
        out[idx] = x[idx] + bias[c] + a[r];
      }
    }
  }
}

// ---------------------------------------------------------------------------
// Kernel 4: flash attention. REVERT of the no-staging experiment (R10: 69µs,
// latency-bound — L2 latency landed on the MFMA chain with only 8 waves/CU).
// Structure: K staged in double-buffered LDS via gload_lds (latency hidden
// across one full iteration); V read DIRECT global->reg, issued right after
// the barrier and consumed after softmax (T14: ~300cy softmax covers L2
// latency). 16 q-rows/wave, 64-row blocks -> 1024 blocks x 4 waves =
// 16 waves/CU (2x the previous TLP). LDS 25.6KB (6 blocks/CU capacity).
// S in log2-domain (Q pre-scaled by 0.125*log2e); defer-max THR=8*log2e.
// ---------------------------------------------------------------------------
__global__ __launch_bounds__(256) void attn_kernel(const BF16* __restrict__ q_t,
                                                   const BF16* __restrict__ k_t,
                                                   const BF16* __restrict__ v_nat,
                                                   BF16* __restrict__ attout) {
  const int L = blockIdx.x;            // 0..1023
  const int b = L & 7, w = L >> 3;     // batch = XCD
  const int hh = w & 7;
  const int i0 = (w >> 3) * 64;        // q-tile base (64 rows, 16 tiles/bh)
  const int bh = b * 8 + hh;
  const int tid = threadIdx.x, l = tid & 63, wv = tid >> 6;
  const int lc = l & 15, lh = l >> 4;

  __shared__ __align__(16) BF16 Kl[2][64 * 64];  // [j][d] chunk-swizzled, 16KB
  __shared__ __align__(16) BF16 Pl[4][16][72];   // per-wave P [q][j], 9KB

  // Q as B-fragment: col=q=lc, k-chunk=lh
  bf16x8 aq0, aq1;
  {
    const BF16* qp = q_t + ((size_t)bh * 1024 + i0 + wv * 16 + lc) * 64;
    aq0 = *(const bf16x8*)&qp[lh * 8];
    aq1 = *(const bf16x8*)&qp[32 + lh * 8];
  }

  f32x4 O[4] = {};
  float mr = -1e30f, lr = 0.f;

  const BF16* kbase = k_t + (size_t)bh * 1024 * 64;    // [j][d]
  const BF16* vbase = v_nat + (size_t)bh * 64 * 1024;  // [d][j]

  // K staging map (512 16B-chunks per tile, 2 rounds of 256 lanes)
  int srow[2], scg[2];
  #pragma unroll
  for (int it = 0; it < 2; ++it) {
    int cidx = it * 256 + tid;
    srow[it] = cidx >> 3;
    scg[it]  = (cidx & 7) ^ (srow[it] & 7);
  }

  // prefetch K tile 0
  #pragma unroll
  for (int it = 0; it < 2; ++it)
    gload_lds16(&kbase[(size_t)srow[it] * 64 + scg[it] * 8],
                &Kl[0][(it * 256 + tid) * 8]);

  for (int jt = 0; jt < 16; ++jt) {
    const int cur = jt & 1;
    const int j0 = jt * 64;
    __syncthreads();   // K tile jt resident; prev iteration's reads done
    if (jt < 15) {
      const int j1 = j0 + 64, nxt = cur ^ 1;
      #pragma unroll
      for (int it = 0; it < 2; ++it)
        gload_lds16(&kbase[(size_t)(j1 + srow[it]) * 64 + scg[it] * 8],
                    &Kl[nxt][(it * 256 + tid) * 8]);
    }

    // issue V fragment loads for THIS tile now; consumed after softmax (T14)
    bf16x8 av[4][2];
    #pragma unroll
    for (int nf = 0; nf < 4; ++nf) {
      const BF16* vrow = vbase + ((size_t)(nf * 16 + lc)) * 1024 + j0;
      av[nf][0] = *(const bf16x8*)&vrow[lh * 8];
      av[nf][1] = *(const bf16x8*)&vrow[32 + lh * 8];
    }

    // S^T = K·Q from Kl[cur]: lane (lc,lh) -> S[q=lc][j=16jf+4lh+r]
    f32x4 Sv[4];
    __builtin_amdgcn_s_setprio(1);
    #pragma unroll
    for (int jf = 0; jf < 4; ++jf) {
      const int jl = jf * 16 + lc;
      const int c0 = lh ^ (jl & 7), c1 = (4 + lh) ^ (jl & 7);
      bf16x8 ak = *(const bf16x8*)&Kl[cur][(jl * 8 + c0) * 8];
      f32x4 s0 = {};
      s0 = __builtin_amdgcn_mfma_f32_16x16x32_bf16(ak, aq0, s0, 0, 0, 0);
      ak = *(const bf16x8*)&Kl[cur][(jl * 8 + c1) * 8];
      Sv[jf] = __builtin_amdgcn_mfma_f32_16x16x32_bf16(ak, aq1, s0, 0, 0, 0);
    }
    __builtin_amdgcn_s_setprio(0);

    // online softmax (defer-max THR = 8*log2e = 11.52)
    float tmax = Sv[0][0];
    #pragma unroll
    for (int jf = 0; jf < 4; ++jf)
      #pragma unroll
      for (int r = 0; r < 4; ++r) tmax = fmaxf(tmax, Sv[jf][r]);
    tmax = fmaxf(tmax, __shfl_xor(tmax, 16, 64));
    tmax = fmaxf(tmax, __shfl_xor(tmax, 32, 64));
    if (__any(tmax > mr + 11.52f)) {
      const float mnew = fmaxf(mr, tmax);
      const float sc = exp2f(mr - mnew);
      mr = mnew;
      lr *= sc;
      #pragma unroll
      for (int nf = 0; nf < 4; ++nf)
        #pragma unroll
        for (int r = 0; r < 4; ++r) O[nf][r] *= sc;
    }
    float rs = 0.f;
    #pragma unroll
    for (int jf = 0; jf < 4; ++jf) {
      ushort4v pk;
      #pragma unroll
      for (int r = 0; r < 4; ++r) {
        float p = exp2f(Sv[jf][r] - mr);
        rs += p;
        pk[r] = f2bf(p);
      }
      *(ushort4v*)&Pl[wv][lc][jf * 16 + 4 * lh] = pk;
    }
    rs += __shfl_xor(rs, 16, 64);
    rs += __shfl_xor(rs, 32, 64);
    lr += rs;

    // P as B-fragment (wave-private LDS transpose, lgkmcnt-ordered)
    const bf16x8 bp0 = *(const bf16x8*)&Pl[wv][lc][lh * 8];
    const bf16x8 bp1 = *(const bf16x8*)&Pl[wv][lc][32 + lh * 8];

    // O^T[d][q] += V^T[d][j] * P[j][q]; av regs loaded ~300cy ago
    __builtin_amdgcn_s_setprio(1);
    #pragma unroll
    for (int nf = 0; nf < 4; ++nf) {
      O[nf] = __builtin_amdgcn_mfma_f32_16x16x32_bf16(av[nf][0], bp0, O[nf], 0, 0, 0);
      O[nf] = __builtin_amdgcn_mfma_f32_16x16x32_bf16(av[nf][1], bp1, O[nf], 0, 0, 0);
    }
    __builtin_amdgcn_s_setprio(0);
  }

  // epilogue: lane holds O[q=lc][d=16nf+4lh+r]
  const float inv = 1.0f / lr;
  BF16* dst = attout + ((size_t)b * 1024 + i0 + wv * 16 + lc) * 512 + hh * 64;
  #pragma unroll
  for (int nf = 0; nf < 4; ++nf) {
    ushort4v pk;
    #pragma unroll
    for (int r = 0; r < 4; ++r) pk[r] = f2bf(O[nf][r] * inv);
    *(ushort4v*)&dst[nf * 16 + 4 * lh] = pk;
  }
}

// ---------------------------------------------------------------------------
extern "C" void kernel_launch(void* const* d_in, const int* in_sizes, int n_in,
                              void* d_out, int out_size, void* d_ws, size_t ws_size,
                              hipStream_t stream) {
  const float* x      = (const float*)d_in[0];
  const float* gn_w   = (const float*)d_in[1];
  const float* gn_b   = (const float*)d_in[2];
  const float* qkv_w  = (const float*)d_in[3];
  const float* qkv_b  = (const float*)d_in[4];
  const float* proj_w = (const float*)d_in[5];
  const float* proj_b = (const float*)d_in[6];
  float* out = (float*)d_out;

  char* ws = (char*)d_ws;
  BF16* wq     = (BF16*)(ws);                    // 1.5 MB
  BF16* wp     = (BF16*)(ws + 1572864);          // 0.5 MB
  BF16* h_t    = (BF16*)(ws + 2097152);          // 8 MB
  BF16* q_t    = (BF16*)(ws + 10485760);         // 8 MB
  BF16* k_t    = (BF16*)(ws + 18874368);         // 8 MB
  BF16* v_nat  = (BF16*)(ws + 27262976);         // 8 MB
  float2* stats = (float2*)(ws + 35651584);      // 32 KB; end = 35684352
  BF16* attout = h_t;  // h_t dead after qkv GEMM; reuse for attention output

  stats_cast_kernel<<<1280, 256, 0, stream>>>(x, gn_w, gn_b, qkv_w, proj_w,
                                              stats, wq, wp);
  gn_apply_kernel<<<256, 256, 0, stream>>>(x, stats, h_t);
  qkv_gemm_kernel<<<768, 256, 0, stream>>>(wq, h_t, qkv_b, q_t, k_t, v_nat);
  attn_kernel<<<1024, 256, 0, stream>>>(q_t, k_t, v_nat, attout);
  proj_gemm_kernel<<<256, 256, 0, stream>>>(wp, attout, proj_b, x, out);
}

// Round 12
// 171.550 us; speedup vs baseline: 1.2160x; 1.2160x over previous
//
#include <hip/hip_runtime.h>
#include <hip/hip_bf16.h>

#define BF16 __hip_bfloat16

typedef __attribute__((ext_vector_type(8))) short bf16x8;
typedef __attribute__((ext_vector_type(4))) float f32x4;
typedef __attribute__((ext_vector_type(4))) unsigned short ushort4v;
typedef __attribute__((ext_vector_type(4))) float float4v;

#define LOG2E 1.44269504089f

__device__ __forceinline__ unsigned short f2bf(float f) {
  BF16 h = __float2bfloat16(f);
  union { BF16 h; unsigned short u; } cv;
  cv.h = h;
  return cv.u;
}

// Direct global->LDS async copy, 16B per lane. LDS dest is wave-uniform base
// + lane*16 (HW rule); swizzling is done on the GLOBAL source address.
__device__ __forceinline__ void gload_lds16(const BF16* g, BF16* s) {
  __builtin_amdgcn_global_load_lds(
      (const __attribute__((address_space(1))) void*)g,
      (__attribute__((address_space(3))) void*)s, 16, 0, 0);
}

// ---------------------------------------------------------------------------
// Kernel 1: fused GroupNorm stats (+per-channel affine precompute) and
// weight fp32->bf16 casts.
// ---------------------------------------------------------------------------
__global__ __launch_bounds__(256) void stats_cast_kernel(const float* __restrict__ x,
                                                         const float* __restrict__ gw,
                                                         const float* __restrict__ gb,
                                                         const float* __restrict__ qw,
                                                         const float* __restrict__ pw,
                                                         float2* __restrict__ stats,
                                                         BF16* __restrict__ wq,
                                                         BF16* __restrict__ wp) {
  const int L = blockIdx.x;
  if (L < 256) {
    const int bb = L & 7, g = L >> 3;   // batch = XCD
    const float* xg = x + (size_t)(bb * 512 + g * 16) * 1024;
    float s = 0.f, ss = 0.f;
    const float4v* x4 = (const float4v*)xg;
    for (int i = threadIdx.x; i < 4096; i += 256) {
      float4v v = x4[i];
      s  += v[0] + v[1] + v[2] + v[3];
      ss += v[0] * v[0] + v[1] * v[1] + v[2] * v[2] + v[3] * v[3];
    }
    for (int off = 32; off > 0; off >>= 1) {
      s  += __shfl_down(s, off, 64);
      ss += __shfl_down(ss, off, 64);
    }
    __shared__ float sred[8];
    const int wv = threadIdx.x >> 6;
    if ((threadIdx.x & 63) == 0) { sred[wv] = s; sred[4 + wv] = ss; }
    __syncthreads();
    const float S  = sred[0] + sred[1] + sred[2] + sred[3];
    const float SS = sred[4] + sred[5] + sred[6] + sred[7];
    const float mean = S * (1.f / 16384.f);
    const float var  = SS * (1.f / 16384.f) - mean * mean;
    const float rstd = rsqrtf(var + 1e-5f);
    if (threadIdx.x < 16) {
      const int c = g * 16 + threadIdx.x;
      const float aw = gw[c] * rstd;
      float2 st; st.x = aw; st.y = gb[c] - mean * aw;
      stats[bb * 512 + c] = st;
    }
  } else {
    const int i4 = (L - 256) * 256 + threadIdx.x;  // float4 index
    if (i4 < 196608) {            // qkv_w: 1536*512/4
      float4v v = ((const float4v*)qw)[i4];
      ushort4v pk;
      #pragma unroll
      for (int r = 0; r < 4; ++r) pk[r] = f2bf(v[r]);
      *(ushort4v*)&wq[i4 * 4] = pk;
    } else {                      // proj_w: 512*512/4
      const int j = i4 - 196608;
      float4v v = ((const float4v*)pw)[j];
      ushort4v pk;
      #pragma unroll
      for (int r = 0; r < 4; ++r) pk[r] = f2bf(v[r]);
      *(ushort4v*)&wp[j * 4] = pk;
    }
  }
}

// ---------------------------------------------------------------------------
// Kernel 2: GroupNorm apply + transpose -> h_t[b][n][c] bf16, coalesced.
// ---------------------------------------------------------------------------
__global__ __launch_bounds__(256) void gn_apply_kernel(const float* __restrict__ x,
                                                       const float2* __restrict__ stats,
                                                       BF16* __restrict__ h_t) {
  const int L = blockIdx.x;           // 0..255
  const int b = L & 7, pxt = L >> 3;  // batch = XCD; 32 px per tile
  const int t = threadIdx.x;
  __shared__ __align__(16) BF16 Lt[128 * 8 * 4];  // 128 ch x 32 px, 8B granules

  for (int ct = 0; ct < 4; ++ct) {    // 128-channel tiles
    if (ct) __syncthreads();
    #pragma unroll
    for (int k = 0; k < 4; ++k) {
      const int i = k * 256 + t;
      const int ch_l = i >> 3, f4l = i & 7;
      const int cg = ct * 128 + ch_l;
      const float2 st = stats[b * 512 + cg];
      const float4v v =
          ((const float4v*)x)[((size_t)(b * 512 + cg)) * 256 + pxt * 8 + f4l];
      ushort4v pk;
      #pragma unroll
      for (int r = 0; r < 4; ++r) pk[r] = f2bf(v[r] * st.x + st.y);
      const int s = f4l ^ (ch_l & 7) ^ ((ch_l >> 3) & 7);
      *(ushort4v*)&Lt[(ch_l * 8 + s) * 4] = pk;
    }
    __syncthreads();
    #pragma unroll
    for (int rr = 0; rr < 2; ++rr) {
      const int px_l = (rr * 256 + t) >> 4;   // 0..31
      const int c16 = t & 15;
      union { unsigned short u[8]; bf16x8 v8; } o;
      #pragma unroll
      for (int cc = 0; cc < 8; ++cc) {
        const int ch = c16 * 8 + cc;
        const int s = (px_l >> 2) ^ (ch & 7) ^ ((ch >> 3) & 7);
        o.u[cc] = *(const unsigned short*)&Lt[(ch * 8 + s) * 4 + (px_l & 3)];
      }
      *(bf16x8*)&h_t[((size_t)(b * 1024 + pxt * 32 + px_l)) * 512 + ct * 128 +
                     c16 * 8] = o.v8;
    }
  }
}

// ---------------------------------------------------------------------------
// GEMM core. Tile 128x128, BK=64, 4 waves, bf16 MFMA; global_load_lds staging
// with inverse chunk-XOR on the global source (m173 pattern).
// ---------------------------------------------------------------------------
#define GEMM_CORE(A, B, Al, Bl)                                                \
  const int tid = threadIdx.x, l = tid & 63, wv = tid >> 6;                    \
  const int wm = wv >> 1, wn = wv & 1;                                         \
  const int lc = l & 15, lh = l >> 4;                                          \
  f32x4 acc[4][4] = {};                                                        \
  int srow[4], scg[4];                                                         \
  _Pragma("unroll")                                                            \
  for (int t = 0; t < 4; ++t) {                                                \
    int cidx = t * 256 + wv * 64 + l;                                          \
    srow[t] = cidx >> 3;                                                       \
    scg[t]  = (cidx & 7) ^ (srow[t] & 7);                                      \
  }                                                                            \
  for (int kt = 0; kt < 8; ++kt) {                                             \
    const int k0 = kt * 64;                                                    \
    __syncthreads();                                                           \
    _Pragma("unroll")                                                          \
    for (int t = 0; t < 4; ++t) {                                              \
      gload_lds16(&A[(size_t)srow[t] * 512 + k0 + scg[t] * 8],                 \
                  &Al[(t * 256 + wv * 64) * 8]);                               \
      gload_lds16(&B[(size_t)srow[t] * 512 + k0 + scg[t] * 8],                 \
                  &Bl[(t * 256 + wv * 64) * 8]);                               \
    }                                                                          \
    __syncthreads();                                                           \
    _Pragma("unroll")                                                          \
    for (int ks = 0; ks < 2; ++ks) {                                           \
      bf16x8 af[4], bfr[4];                                                    \
      _Pragma("unroll")                                                        \
      for (int i = 0; i < 4; ++i) {                                            \
        int rA = wm * 64 + i * 16 + lc;                                        \
        int cA = (ks * 4 + lh) ^ (rA & 7);                                     \
        af[i] = *(const bf16x8*)&Al[(rA * 8 + cA) * 8];                        \
        int rB = wn * 64 + i * 16 + lc;                                        \
        int cB = (ks * 4 + lh) ^ (rB & 7);                                     \
        bfr[i] = *(const bf16x8*)&Bl[(rB * 8 + cB) * 8];                       \
      }                                                                        \
      _Pragma("unroll")                                                        \
      for (int i = 0; i < 4; ++i)                                              \
        _Pragma("unroll")                                                      \
        for (int j = 0; j < 4; ++j)                                            \
          acc[i][j] = __builtin_amdgcn_mfma_f32_16x16x32_bf16(af[i], bfr[j],   \
                                                              acc[i][j], 0, 0, 0); \
    }                                                                          \
  }

// QKV GEMM: A = qkv_w bf16 [1536][512]; B = h_t[b] [1024][512].
// Epilogue stages output tile in LDS and writes fully coalesced.
__global__ __launch_bounds__(256) void qkv_gemm_kernel(const BF16* __restrict__ Wq,
                                                       const BF16* __restrict__ Ht,
                                                       const float* __restrict__ bias,
                                                       BF16* __restrict__ q_t,
                                                       BF16* __restrict__ k_t,
                                                       BF16* __restrict__ v_nat) {
  const int L = blockIdx.x;            // 0..767
  const int b = L & 7, w = L >> 3;     // batch = XCD
  const int mt = w % 12, nt = w / 12;
  const int m0 = mt * 128, n0 = nt * 128;
  const BF16* A = Wq + (size_t)m0 * 512;
  const BF16* B = Ht + (size_t)b * 1024 * 512 + (size_t)n0 * 512;
  __shared__ __align__(16) BF16 smem[16384];
  BF16* Al = smem;
  BF16* Bl = smem + 8192;
  GEMM_CORE(A, B, Al, Bl)

  __syncthreads();                     // all frag reads done; reuse smem
  BF16* Et = smem;                     // 16384 BF16 = 32 KiB
  if (mt < 8) {
    const float scale = (mt < 4) ? 0.125f * LOG2E : 1.0f;
    #pragma unroll
    for (int mi = 0; mi < 4; ++mi) {
      const int d0 = mi * 16 + 4 * lh;          // 0..63
      const int o  = m0 + wm * 64 + d0;
      const int g  = d0 >> 3;
      #pragma unroll
      for (int ni = 0; ni < 4; ++ni) {
        const int pixl = wn * 64 + ni * 16 + lc;
        f32x4 a = acc[mi][ni];
        ushort4v pk;
        #pragma unroll
        for (int r = 0; r < 4; ++r) pk[r] = f2bf((a[r] + bias[o + r]) * scale);
        const int s = g ^ (pixl & 7);
        *(ushort4v*)&Et[((wm * 128 + pixl) * 8 + s) * 8 + (d0 & 7)] = pk;
      }
    }
    __syncthreads();
    BF16* dstb = (mt < 4) ? q_t : k_t;
    const int hb0 = (mt & 3) * 2;
    #pragma unroll
    for (int rr = 0; rr < 8; ++rr) {
      const int rowI = rr * 32 + (tid >> 3);    // 0..255
      const int h2 = rowI >> 7, pixl = rowI & 127;
      const int j = tid & 7;
      bf16x8 v = *(const bf16x8*)&Et[(rowI * 8 + (j ^ (pixl & 7))) * 8];
      *(bf16x8*)&dstb[((size_t)(b * 8 + hb0 + h2) * 1024 + n0 + pixl) * 64 +
                      j * 8] = v;
    }
  } else {
    // V: stage [vr_l][pixl] (128x128)
    #pragma unroll
    for (int mi = 0; mi < 4; ++mi) {
      #pragma unroll
      for (int ni = 0; ni < 4; ++ni) {
        const int pixl = wn * 64 + ni * 16 + lc;
        const int gp = pixl >> 3;
        f32x4 a = acc[mi][ni];
        #pragma unroll
        for (int r = 0; r < 4; ++r) {
          const int vr_l = wm * 64 + mi * 16 + 4 * lh + r;
          const int s = gp ^ (vr_l & 15);
          Et[(vr_l * 16 + s) * 8 + (pixl & 7)] =
              __float2bfloat16(a[r] + bias[m0 + vr_l]);
        }
      }
    }
    __syncthreads();
    const int vr0 = m0 - 1024;
    #pragma unroll
    for (int rr = 0; rr < 8; ++rr) {
      const int vr_l = rr * 16 + (tid >> 4);
      const int gp = tid & 15;
      bf16x8 v = *(const bf16x8*)&Et[(vr_l * 16 + (gp ^ (vr_l & 15))) * 8];
      *(bf16x8*)&v_nat[((size_t)(b * 512 + vr0 + vr_l)) * 1024 + n0 + gp * 8] = v;
    }
  }
}

// Proj GEMM + bias + residual. XCD-swizzled: batch == XCD.
// NEW epilogue: stage each 64x128 fp32 half-tile in LDS, then flat-indexed
// read-back so x loads and out stores are 256B-contiguous per wave-instr
// (was 64B fragments split over 4 c-rows).
__global__ __launch_bounds__(256) void proj_gemm_kernel(const BF16* __restrict__ Wp,
                                                        const BF16* __restrict__ At,
                                                        const float* __restrict__ bias,
                                                        const float* __restrict__ x,
                                                        float* __restrict__ out) {
  const int L = blockIdx.x;            // 0..255
  const int b = L & 7, w = L >> 3;
  const int mt = w & 3, nt = w >> 2;
  const int m0 = mt * 128, n0 = nt * 128;
  const BF16* A = Wp + (size_t)m0 * 512;
  const BF16* B = At + (size_t)b * 1024 * 512 + (size_t)n0 * 512;
  __shared__ __align__(16) BF16 smem[16384];
  BF16* Al = smem;
  BF16* Bl = smem + 8192;
  GEMM_CORE(A, B, Al, Bl)

  float* Ls = (float*)smem;            // 8192 floats = 32 KiB, [64][128]
  #pragma unroll
  for (int h = 0; h < 2; ++h) {
    __syncthreads();                   // h=0: GEMM frag reads done; h=1: reads of Ls done
    if (wm == h) {                     // waves with wm==h own c-rows [h*64, h*64+64)
      #pragma unroll
      for (int mi = 0; mi < 4; ++mi) {
        #pragma unroll
        for (int ni = 0; ni < 4; ++ni) {
          f32x4 a = acc[mi][ni];
          const int nl = wn * 64 + ni * 16 + lc;
          #pragma unroll
          for (int r = 0; r < 4; ++r) {
            const int cl = mi * 16 + 4 * lh + r;
            Ls[cl * 128 + nl] = a[r] + bias[m0 + h * 64 + cl];
          }
        }
      }
    }
    __syncthreads();
    const float* xb = x + ((size_t)(b * 512 + m0 + h * 64)) * 1024 + n0;
    float* ob = out + ((size_t)(b * 512 + m0 + h * 64)) * 1024 + n0;
    #pragma unroll 4
    for (int rr = 0; rr < 32; ++rr) {
      const int idx = rr * 256 + tid;  // 0..8191 over [64][128]
      const int cl = idx >> 7, nl = idx & 127;
      ob[(size_t)cl * 1024 + nl] = Ls[idx] + xb[(size_t)cl * 1024 + nl];
    }
  }
}

// ---------------------------------------------------------------------------
// Kernel 4: flash attention — REVERT to the round-7 measured version (47 µs).
// 128 q-rows/block, 4 waves x 2 col-blocks; K AND V staged in double-buffered
// LDS via gload_lds (one barrier/iter; prefetch flies under full iteration).
// R10 (no staging, 69µs) and R11 (V-direct + K-gload_lds, 84µs) both
// regressed: direct loads put L2 latency on the MFMA chain / vmcnt-entangle
// with the prefetch queue. S in log2-domain; defer-max THR=8*log2e.
// ---------------------------------------------------------------------------
__global__ __launch_bounds__(256) void attn_kernel(const BF16* __restrict__ q_t,
                                                   const BF16* __restrict__ k_t,
                                                   const BF16* __restrict__ v_nat,
                                                   BF16* __restrict__ attout) {
  const int L = blockIdx.x;            // 0..511
  const int xcd = L & 7, w = L >> 3;
  const int b = xcd, hh = w & 7;       // batch = XCD
  const int bh = b * 8 + hh;
  const int i0 = (w >> 3) * 128;
  const int tid = threadIdx.x, l = tid & 63, wv = tid >> 6;
  const int lc = l & 15, lh = l >> 4;

  __shared__ __align__(16) BF16 Kl[2][64 * 64];   // [j][d], chunk-swizzled
  __shared__ __align__(16) BF16 Vl[2][64 * 64];   // [d][j], chunk-swizzled
  __shared__ __align__(16) BF16 Pl[4][2][16][72]; // per-wave/cb P [q][j]

  bf16x8 aq[2][2];
  #pragma unroll
  for (int cb = 0; cb < 2; ++cb) {
    const BF16* qp = q_t + ((size_t)bh * 1024 + i0 + wv * 32 + cb * 16 + lc) * 64;
    aq[cb][0] = *(const bf16x8*)&qp[lh * 8];
    aq[cb][1] = *(const bf16x8*)&qp[32 + lh * 8];
  }

  f32x4 O[2][4] = {};
  float mr[2] = {-1e30f, -1e30f}, lr[2] = {0.f, 0.f};

  const BF16* kbase = k_t + (size_t)bh * 1024 * 64;
  const BF16* vbase = v_nat + (size_t)bh * 64 * 1024;

  int srow[2], scg[2];
  #pragma unroll
  for (int it = 0; it < 2; ++it) {
    int cidx = it * 256 + wv * 64 + l;
    srow[it] = cidx >> 3;
    scg[it]  = (cidx & 7) ^ (srow[it] & 7);
  }

  #pragma unroll
  for (int it = 0; it < 2; ++it) {
    gload_lds16(&kbase[(size_t)srow[it] * 64 + scg[it] * 8],
                &Kl[0][(it * 256 + wv * 64) * 8]);
    gload_lds16(&vbase[(size_t)srow[it] * 1024 + scg[it] * 8],
                &Vl[0][(it * 256 + wv * 64) * 8]);
  }

  for (int jt = 0; jt < 16; ++jt) {
    const int cur = jt & 1;
    __syncthreads();
    if (jt < 15) {
      const int j1 = (jt + 1) * 64, nxt = cur ^ 1;
      #pragma unroll
      for (int it = 0; it < 2; ++it) {
        gload_lds16(&kbase[(size_t)(j1 + srow[it]) * 64 + scg[it] * 8],
                    &Kl[nxt][(it * 256 + wv * 64) * 8]);
        gload_lds16(&vbase[(size_t)srow[it] * 1024 + j1 + scg[it] * 8],
                    &Vl[nxt][(it * 256 + wv * 64) * 8]);
      }
    }

    f32x4 Sv[2][4];
    __builtin_amdgcn_s_setprio(1);
    #pragma unroll
    for (int jf = 0; jf < 4; ++jf) {
      const int jl = jf * 16 + lc;
      const int c0 = lh ^ (jl & 7), c1 = (4 + lh) ^ (jl & 7);
      bf16x8 ak0 = *(const bf16x8*)&Kl[cur][(jl * 8 + c0) * 8];
      bf16x8 ak1 = *(const bf16x8*)&Kl[cur][(jl * 8 + c1) * 8];
      #pragma unroll
      for (int cb = 0; cb < 2; ++cb) {
        f32x4 s0 = {};
        s0 = __builtin_amdgcn_mfma_f32_16x16x32_bf16(ak0, aq[cb][0], s0, 0, 0, 0);
        Sv[cb][jf] = __builtin_amdgcn_mfma_f32_16x16x32_bf16(ak1, aq[cb][1], s0, 0, 0, 0);
      }
    }
    __builtin_amdgcn_s_setprio(0);

    #pragma unroll
    for (int cb = 0; cb < 2; ++cb) {
      float tmax = Sv[cb][0][0];
      #pragma unroll
      for (int jf = 0; jf < 4; ++jf)
        #pragma unroll
        for (int r = 0; r < 4; ++r) tmax = fmaxf(tmax, Sv[cb][jf][r]);
      tmax = fmaxf(tmax, __shfl_xor(tmax, 16, 64));
      tmax = fmaxf(tmax, __shfl_xor(tmax, 32, 64));
      if (__any(tmax > mr[cb] + 11.52f)) {
        const float mnew = fmaxf(mr[cb], tmax);
        const float sc = exp2f(mr[cb] - mnew);
        mr[cb] = mnew;
        lr[cb] *= sc;
        #pragma unroll
        for (int nf = 0; nf < 4; ++nf)
          #pragma unroll
          for (int r = 0; r < 4; ++r) O[cb][nf][r] *= sc;
      }
      float rs = 0.f;
      #pragma unroll
      for (int jf = 0; jf < 4; ++jf) {
        ushort4v pk;
        #pragma unroll
        for (int r = 0; r < 4; ++r) {
          float p = exp2f(Sv[cb][jf][r] - mr[cb]);
          rs += p;
          pk[r] = f2bf(p);
        }
        *(ushort4v*)&Pl[wv][cb][lc][jf * 16 + 4 * lh] = pk;
      }
      rs += __shfl_xor(rs, 16, 64);
      rs += __shfl_xor(rs, 32, 64);
      lr[cb] += rs;
    }

    bf16x8 bp[2][2];
    #pragma unroll
    for (int cb = 0; cb < 2; ++cb) {
      bp[cb][0] = *(const bf16x8*)&Pl[wv][cb][lc][lh * 8];
      bp[cb][1] = *(const bf16x8*)&Pl[wv][cb][lc][32 + lh * 8];
    }

    __builtin_amdgcn_s_setprio(1);
    #pragma unroll
    for (int nf = 0; nf < 4; ++nf) {
      const int dl = nf * 16 + lc;
      const int c0 = lh ^ (dl & 7), c1 = (4 + lh) ^ (dl & 7);
      bf16x8 av0 = *(const bf16x8*)&Vl[cur][(dl * 8 + c0) * 8];
      bf16x8 av1 = *(const bf16x8*)&Vl[cur][(dl * 8 + c1) * 8];
      #pragma unroll
      for (int cb = 0; cb < 2; ++cb) {
        O[cb][nf] = __builtin_amdgcn_mfma_f32_16x16x32_bf16(av0, bp[cb][0], O[cb][nf], 0, 0, 0);
        O[cb][nf] = __builtin_amdgcn_mfma_f32_16x16x32_bf16(av1, bp[cb][1], O[cb][nf], 0, 0, 0);
      }
    }
    __builtin_amdgcn_s_setprio(0);
  }

  #pragma unroll
  for (int cb = 0; cb < 2; ++cb) {
    const float inv = 1.0f / lr[cb];
    BF16* dst = attout + ((size_t)b * 1024 + i0 + wv * 32 + cb * 16 + lc) * 512 + hh * 64;
    #pragma unroll
    for (int nf = 0; nf < 4; ++nf) {
      ushort4v pk;
      #pragma unroll
      for (int r = 0; r < 4; ++r) pk[r] = f2bf(O[cb][nf][r] * inv);
      *(ushort4v*)&dst[nf * 16 + 4 * lh] = pk;
    }
  }
}

// ---------------------------------------------------------------------------
extern "C" void kernel_launch(void* const* d_in, const int* in_sizes, int n_in,
                              void* d_out, int out_size, void* d_ws, size_t ws_size,
                              hipStream_t stream) {
  const float* x      = (const float*)d_in[0];
  const float* gn_w   = (const float*)d_in[1];
  const float* gn_b   = (const float*)d_in[2];
  const float* qkv_w  = (const float*)d_in[3];
  const float* qkv_b  = (const float*)d_in[4];
  const float* proj_w = (const float*)d_in[5];
  const float* proj_b = (const float*)d_in[6];
  float* out = (float*)d_out;

  char* ws = (char*)d_ws;
  BF16* wq     = (BF16*)(ws);                    // 1.5 MB
  BF16* wp     = (BF16*)(ws + 1572864);          // 0.5 MB
  BF16* h_t    = (BF16*)(ws + 2097152);          // 8 MB
  BF16* q_t    = (BF16*)(ws + 10485760);         // 8 MB
  BF16* k_t    = (BF16*)(ws + 18874368);         // 8 MB
  BF16* v_nat  = (BF16*)(ws + 27262976);         // 8 MB
  float2* stats = (float2*)(ws + 35651584);      // 32 KB; end = 35684352
  BF16* attout = h_t;  // h_t dead after qkv GEMM; reuse for attention output

  stats_cast_kernel<<<1280, 256, 0, stream>>>(x, gn_w, gn_b, qkv_w, proj_w,
                                              stats, wq, wp);
  gn_apply_kernel<<<256, 256, 0, stream>>>(x, stats, h_t);
  qkv_gemm_kernel<<<768, 256, 0, stream>>>(wq, h_t, qkv_b, q_t, k_t, v_nat);
  attn_kernel<<<512, 256, 0, stream>>>(q_t, k_t, v_nat, attout);
  proj_gemm_kernel<<<256, 256, 0, stream>>>(wp, attout, proj_b, x, out);
}